// Round 6
// baseline (828.316 us; speedup 1.0000x reference)
//
#include <hip/hip_runtime.h>
#include <hip/hip_cooperative_groups.h>

namespace cg = cooperative_groups;

// Problem constants (match reference)
static constexpr int DIM = 128;
static constexpr int N = DIM * DIM * DIM;        // 2,097,152 voxels
static constexpr int ITERS = 20;
static constexpr float EPS = 1e-6f;

// Gaussian(sigma=1, radius=3) normalized weights
#define W0 0.39905028f
#define W1 0.24203624f
#define W2 0.05400559f
#define W3 0.00443305f

__device__ __forceinline__ int clamp_i(int v, int lo, int hi) {
    return min(max(v, lo), hi);
}

// Non-temporal helpers: vf is a pure stream in both phases (read once per
// iter in forces, written once in zblur, consumed only next iteration).
// Bypassing L2 for it keeps the REUSED strips resident:
//   phase 1: w/f strips (x3 z-plane reuse)  -> the ~30 MB/iter excess fetch
//   phase 2: u2 strip (x1.75 z-halo reuse) + mov strip
// NOTE: __builtin_nontemporal_load requires a clang-native vector type, not
// HIP_vector_type<float,4> (R5 compile failure) — use ext_vector_type(4).
typedef float vfloat4 __attribute__((ext_vector_type(4)));

__device__ __forceinline__ float4 nt_load4(const float* p) {
    vfloat4 v = __builtin_nontemporal_load((const vfloat4*)p);
    return make_float4(v.x, v.y, v.z, v.w);
}
__device__ __forceinline__ void nt_store1(float* p, float v) {
    __builtin_nontemporal_store(v, p);
}

// ---------------------------------------------------------------------------
// Phase 1: fused forces (all 3 channels) + x-blur (register shuffles) +
// y-blur (LDS). x-halo scalars via lane shuffles (lane i-1's .w == [idx-1];
// lane-0/31 garbage only feeds the unused one-sided select arms).
//
// Block b -> (z = b>>3, y0 = (b&7)*16): XCD k owns y-strip k for all z
// (R1: -10% via L2 locality).
// LDS = 3*22*132*4 = 34848 B -> 4 blocks/CU; __launch_bounds__(256,4)
// caps VGPR so 1024 blocks are exactly co-resident (cooperative).
// ---------------------------------------------------------------------------
#define ROWS 22            // 16 + 2*3 halo
#define SSTR 132           // padded row stride (floats), 16B-aligned
#define SC(c, r) ((((c) * ROWS) + (r)) * SSTR)
#define LDS_FLOATS (3 * ROWS * SSTR)

__device__ __forceinline__ void forces_phase(const float* __restrict__ wpd,
                                             const float* __restrict__ fix,
                                             const float* __restrict__ vf,
                                             float* __restrict__ u2,
                                             float* S, bool first, int b) {
    int z  = b >> 3;
    int y0 = (b & 7) << 4;

    // ---- Stage A+B: forces + x-blur -> S (704 items = 11 full waves)
    for (int e = threadIdx.x; e < ROWS * 32; e += 256) {
        int x4 = e & 31;
        int r  = e >> 5;
        int gy = y0 + r - 3;
        float4 rz = make_float4(0, 0, 0, 0);
        float4 ry = make_float4(0, 0, 0, 0);
        float4 rx = make_float4(0, 0, 0, 0);
        if (gy >= 0 && gy < 128) {
            int idx = (z << 14) + (gy << 7) + (x4 << 2);
            int xb = x4 << 2;

            float4 wc4 = *(const float4*)(wpd + idx);
            float4 fc4 = *(const float4*)(fix + idx);

            int iyp = (gy < 127) ? idx + 128   : idx;
            int iym = (gy > 0)   ? idx - 128   : idx;
            int izp = (z < 127)  ? idx + 16384 : idx;
            int izm = (z > 0)    ? idx - 16384 : idx;

            float4 wyp = *(const float4*)(wpd + iyp), wym = *(const float4*)(wpd + iym);
            float4 wzp = *(const float4*)(wpd + izp), wzm = *(const float4*)(wpd + izm);
            float4 fyp = *(const float4*)(fix + iyp), fym = *(const float4*)(fix + iym);
            float4 fzp = *(const float4*)(fix + izp), fzm = *(const float4*)(fix + izm);

            // x-halo via shuffle (replaces 4 scalar loads). Lane 0/31 (and
            // cross-row lane-32 boundary) garbage only reaches the unused
            // xi==0 / xi==127 one-sided arms.
            float wl = __shfl_up(wc4.w, 1);
            float wr = __shfl_down(wc4.x, 1);
            float fl = __shfl_up(fc4.w, 1);
            float fr = __shfl_down(fc4.x, 1);

            float wcv[4] = {wc4.x, wc4.y, wc4.z, wc4.w};
            float fcv[4] = {fc4.x, fc4.y, fc4.z, fc4.w};
            float wypv[4] = {wyp.x, wyp.y, wyp.z, wyp.w};
            float wymv[4] = {wym.x, wym.y, wym.z, wym.w};
            float wzpv[4] = {wzp.x, wzp.y, wzp.z, wzp.w};
            float wzmv[4] = {wzm.x, wzm.y, wzm.z, wzm.w};
            float fypv[4] = {fyp.x, fyp.y, fyp.z, fyp.w};
            float fymv[4] = {fym.x, fym.y, fym.z, fym.w};
            float fzpv[4] = {fzp.x, fzp.y, fzp.z, fzp.w};
            float fzmv[4] = {fzm.x, fzm.y, fzm.z, fzm.w};

            // vf: read-once stream -> non-temporal (don't evict w/f strips)
            float4 vz4 = first ? make_float4(0, 0, 0, 0) : nt_load4(vf + idx);
            float4 vy4 = first ? make_float4(0, 0, 0, 0) : nt_load4(vf + N + idx);
            float4 vx4 = first ? make_float4(0, 0, 0, 0) : nt_load4(vf + 2 * N + idx);
            float vzv[4] = {vz4.x, vz4.y, vz4.z, vz4.w};
            float vyv[4] = {vy4.x, vy4.y, vy4.z, vy4.w};
            float vxv[4] = {vx4.x, vx4.y, vx4.z, vx4.w};

            float ozv[4], oyv[4], oxv[4];
#pragma unroll
            for (int i = 0; i < 4; ++i) {
                float wc = wcv[i], fc = fcv[i];
                float diff = wc - fc;

                float gwz = (z == 0)   ? (wzpv[i] - wc)
                          : (z == 127) ? (wc - wzmv[i])
                          : 0.5f * (wzpv[i] - wzmv[i]);
                float gfz = (z == 0)   ? (fzpv[i] - fc)
                          : (z == 127) ? (fc - fzmv[i])
                          : 0.5f * (fzpv[i] - fzmv[i]);
                float grz = 0.5f * (gwz + gfz);

                float gwy = (gy == 0)   ? (wypv[i] - wc)
                          : (gy == 127) ? (wc - wymv[i])
                          : 0.5f * (wypv[i] - wymv[i]);
                float gfy = (gy == 0)   ? (fypv[i] - fc)
                          : (gy == 127) ? (fc - fymv[i])
                          : 0.5f * (fypv[i] - fymv[i]);
                float gry = 0.5f * (gwy + gfy);

                float wleft  = (i == 0) ? wl : wcv[i - 1];
                float wright = (i == 3) ? wr : wcv[i + 1];
                float fleft  = (i == 0) ? fl : fcv[i - 1];
                float fright = (i == 3) ? fr : fcv[i + 1];
                int xi = xb + i;
                float gwx = (xi == 0)   ? (wright - wc)
                          : (xi == 127) ? (wc - wleft)
                          : 0.5f * (wright - wleft);
                float gfx = (xi == 0)   ? (fright - fc)
                          : (xi == 127) ? (fc - fleft)
                          : 0.5f * (fright - fleft);
                float grx = 0.5f * (gwx + gfx);

                float denom = grz * grz + gry * gry + grx * grx + diff * diff;
                float s = (denom > EPS) ? (diff / denom) : 0.0f;
                ozv[i] = vzv[i] + s * grz;
                oyv[i] = vyv[i] + s * gry;
                oxv[i] = vxv[i] + s * grx;
            }
            rz = make_float4(ozv[0], ozv[1], ozv[2], ozv[3]);
            ry = make_float4(oyv[0], oyv[1], oyv[2], oyv[3]);
            rx = make_float4(oxv[0], oxv[1], oxv[2], oxv[3]);
        }

        // x-blur in registers via lane shuffles (all 64 lanes active here;
        // OOB rows carry zeros = zero-pad).
        float4 vch[3] = {rz, ry, rx};
#pragma unroll
        for (int c = 0; c < 3; ++c) {
            float4 v0 = vch[c];
            float4 m1, p1;
            m1.x = __shfl_up(v0.x, 1);  m1.y = __shfl_up(v0.y, 1);
            m1.z = __shfl_up(v0.z, 1);  m1.w = __shfl_up(v0.w, 1);
            p1.x = __shfl_down(v0.x, 1); p1.y = __shfl_down(v0.y, 1);
            p1.z = __shfl_down(v0.z, 1); p1.w = __shfl_down(v0.w, 1);
            if (x4 == 0)  m1 = make_float4(0, 0, 0, 0);
            if (x4 == 31) p1 = make_float4(0, 0, 0, 0);
            float w[12] = {m1.x, m1.y, m1.z, m1.w,
                           v0.x, v0.y, v0.z, v0.w,
                           p1.x, p1.y, p1.z, p1.w};
            float o[4];
#pragma unroll
            for (int i = 0; i < 4; ++i) {
                o[i] = W3 * (w[i + 1] + w[i + 7]) + W2 * (w[i + 2] + w[i + 6])
                     + W1 * (w[i + 3] + w[i + 5]) + W0 * w[i + 4];
            }
            *(float4*)(S + SC(c, r) + (x4 << 2)) = make_float4(o[0], o[1], o[2], o[3]);
        }
    }
    __syncthreads();

    // ---- Stage C: y-blur S -> global u2 (16 rows x 32 float4 x 3 ch)
    for (int e = threadIdx.x; e < 16 * 32 * 3; e += 256) {
        int x4 = e & 31;
        int t2 = e >> 5;
        int y  = t2 & 15;
        int c  = t2 >> 4;
        const float* base = S + SC(c, y) + (x4 << 2);   // rows y..y+6 (halo offset)
        float4 v0 = *(const float4*)(base);
        float4 v1 = *(const float4*)(base + 1 * SSTR);
        float4 v2 = *(const float4*)(base + 2 * SSTR);
        float4 v3 = *(const float4*)(base + 3 * SSTR);
        float4 v4 = *(const float4*)(base + 4 * SSTR);
        float4 v5 = *(const float4*)(base + 5 * SSTR);
        float4 v6 = *(const float4*)(base + 6 * SSTR);
        float4 acc;
        acc.x = W3 * (v0.x + v6.x) + W2 * (v1.x + v5.x) + W1 * (v2.x + v4.x) + W0 * v3.x;
        acc.y = W3 * (v0.y + v6.y) + W2 * (v1.y + v5.y) + W1 * (v2.y + v4.y) + W0 * v3.y;
        acc.z = W3 * (v0.z + v6.z) + W2 * (v1.z + v5.z) + W1 * (v2.z + v4.z) + W0 * v3.z;
        acc.w = W3 * (v0.w + v6.w) + W2 * (v1.w + v5.w) + W1 * (v2.w + v4.w) + W0 * v3.w;
        // u2 store stays CACHED: phase 2 of the same XCD re-reads it x1.75.
        *(float4*)(u2 + (size_t)c * N + ((size_t)z << 14) + ((y0 + y) << 7) + (x4 << 2)) = acc;
    }
}

// ---------------------------------------------------------------------------
// Phase 2: fused z-blur + trilinear warp. One thread owns an (x,y) column
// x 8-z chunk for ALL 3 channels. y-strip-aligned XCD remap (bijective)
// keeps u2 z-halo re-reads in the same XCD's L2 and aligns produced
// vf/warped strips with phase-1 consumers.
// ---------------------------------------------------------------------------
__device__ __forceinline__ void zblur_phase(const float* __restrict__ u2,
                                            const float* __restrict__ mov,
                                            float* __restrict__ vf,
                                            float* __restrict__ warped,
                                            bool do_warp, int b) {
    int k  = b & 7;
    int j  = b >> 3;
    int lb = ((j & 15) << 6) + (k << 3) + (j >> 4);
    int g  = lb * 256 + threadIdx.x;          // 0 .. 262143 (bijective remap)
    int col = g & 16383;                      // (y<<7)|x
    int zc  = g >> 14;                        // 0..15
    int z0  = zc << 3;
    int x = col & 127, y = col >> 7;

    float bz[3][8];
#pragma unroll
    for (int c = 0; c < 3; ++c) {
        const float* inp = u2 + (size_t)c * N + col;
        float win[14];
#pragma unroll
        for (int i = 0; i < 14; ++i) {
            int zz = z0 - 3 + i;
            win[i] = (zz >= 0 && zz < 128) ? inp[(size_t)zz << 14] : 0.0f;
        }
#pragma unroll
        for (int k8 = 0; k8 < 8; ++k8) {
            bz[c][k8] = W3 * (win[k8] + win[k8 + 6]) + W2 * (win[k8 + 1] + win[k8 + 5])
                      + W1 * (win[k8 + 2] + win[k8 + 4]) + W0 * win[k8 + 3];
        }
        float* outp = vf + (size_t)c * N + col;
        // vf store: consumed once next iteration -> non-temporal (don't
        // evict u2/mov strips from this XCD's L2).
#pragma unroll
        for (int k8 = 0; k8 < 8; ++k8)
            nt_store1(outp + ((size_t)(z0 + k8) << 14), bz[c][k8]);
    }

    if (do_warp) {
        for (int k8 = 0; k8 < 8; ++k8) {
            int z = z0 + k8;
            float cz = (float)z + bz[0][k8];
            float cy = (float)y + bz[1][k8];
            float cx = (float)x + bz[2][k8];

            float flz = floorf(cz), fly = floorf(cy), flx = floorf(cx);
            float fz = cz - flz, fy = cy - fly, fx = cx - flx;

            int zi = (int)flz, yi = (int)fly, xi = (int)flx;
            int z0c = clamp_i(zi, 0, DIM - 1), z1c = clamp_i(zi + 1, 0, DIM - 1);
            int y0c = clamp_i(yi, 0, DIM - 1), y1c = clamp_i(yi + 1, 0, DIM - 1);
            int x0c = clamp_i(xi, 0, DIM - 1), x1c = clamp_i(xi + 1, 0, DIM - 1);

            int b00 = (z0c << 14) + (y0c << 7);
            int b01 = (z0c << 14) + (y1c << 7);
            int b10 = (z1c << 14) + (y0c << 7);
            int b11 = (z1c << 14) + (y1c << 7);

            float v000 = mov[b00 + x0c], v001 = mov[b00 + x1c];
            float v010 = mov[b01 + x0c], v011 = mov[b01 + x1c];
            float v100 = mov[b10 + x0c], v101 = mov[b10 + x1c];
            float v110 = mov[b11 + x0c], v111 = mov[b11 + x1c];

            float c00 = v000 + fx * (v001 - v000);
            float c01 = v010 + fx * (v011 - v010);
            float c10 = v100 + fx * (v101 - v100);
            float c11 = v110 + fx * (v111 - v110);
            float c0 = c00 + fy * (c01 - c00);
            float c1 = c10 + fy * (c11 - c10);
            // warped store stays CACHED: next iteration's phase 1 on the
            // same XCD reads it x~4 (z+-1, y-halo).
            warped[((size_t)z << 14) + col] = c0 + fz * (c1 - c0);
        }
    }
}

// ---------------------------------------------------------------------------
// Persistent cooperative kernel — all 20 iterations in ONE launch,
// grid.sync() between phases. 1024 blocks x 256 threads = exactly
// 4 blocks/CU x 256 CU co-resident (LDS 34848 B, VGPR<=128).
// ---------------------------------------------------------------------------
__global__ __launch_bounds__(256, 4) void demons_persistent(const float* mov,
                                                            const float* fix,
                                                            float* vf,
                                                            float* warped,
                                                            float* u2) {
    cg::grid_group grid = cg::this_grid();
    __shared__ float S[LDS_FLOATS];
    int b = blockIdx.x;

    for (int it = 0; it < ITERS; ++it) {
        bool first = (it == 0);
        forces_phase(first ? mov : warped, fix, vf, u2, S, first, b);
        grid.sync();                                   // u2 complete
        zblur_phase(u2, mov, vf, warped, it < ITERS - 1, b);
        if (it < ITERS - 1) grid.sync();               // vf/warped complete
    }
}

// ---------------------------------------------------------------------------
// Fallback path (proven R2 structure): separate launches per phase.
// ---------------------------------------------------------------------------
template <bool FIRST>
__global__ __launch_bounds__(256, 4) void forces_xy_kernel(const float* __restrict__ wpd,
                                                           const float* __restrict__ fix,
                                                           const float* __restrict__ vf,
                                                           float* __restrict__ u2) {
    __shared__ float S[LDS_FLOATS];
    forces_phase(wpd, fix, vf, u2, S, FIRST, blockIdx.x);
}

template <bool DO_WARP>
__global__ __launch_bounds__(256, 4) void zblur_warp_kernel(const float* __restrict__ u2,
                                                            const float* __restrict__ mov,
                                                            float* __restrict__ vf,
                                                            float* __restrict__ warped) {
    zblur_phase(u2, mov, vf, warped, DO_WARP, blockIdx.x);
}

extern "C" void kernel_launch(void* const* d_in, const int* in_sizes, int n_in,
                              void* d_out, int out_size, void* d_ws, size_t ws_size,
                              hipStream_t stream) {
    const float* mov = (const float*)d_in[0];
    const float* fix = (const float*)d_in[1];
    float* vf = (float*)d_out;          // (3, N) — lives in d_out throughout
    float* ws = (float*)d_ws;
    float* warped = ws;                 // N floats
    float* u2     = ws + (size_t)N;     // 3N floats (xy-blurred forces)

    const int BLK = 256;
    const int GRID = 1024;

    // Decide cooperative support once (host-only queries; graph-capture safe).
    static int coop_ok = -1;
    if (coop_ok < 0) {
        int dev = 0;
        (void)hipGetDevice(&dev);
        int coop = 0;
        (void)hipDeviceGetAttribute(&coop, hipDeviceAttributeCooperativeLaunch, dev);
        int ncu = 0;
        (void)hipDeviceGetAttribute(&ncu, hipDeviceAttributeMultiprocessorCount, dev);
        int occ = 0;
        (void)hipOccupancyMaxActiveBlocksPerMultiprocessor(&occ, demons_persistent, BLK, 0);
        coop_ok = (coop && (long long)occ * ncu >= GRID) ? 1 : 0;
    }

    if (coop_ok) {
        void* args[] = {(void*)&mov, (void*)&fix, (void*)&vf, (void*)&warped, (void*)&u2};
        (void)hipLaunchCooperativeKernel(demons_persistent, dim3(GRID), dim3(BLK),
                                         args, 0, stream);
    } else {
        forces_xy_kernel<true><<<GRID, BLK, 0, stream>>>(mov, fix, nullptr, u2);
        zblur_warp_kernel<true><<<GRID, BLK, 0, stream>>>(u2, mov, vf, warped);
        for (int it = 1; it < ITERS - 1; ++it) {
            forces_xy_kernel<false><<<GRID, BLK, 0, stream>>>(warped, fix, vf, u2);
            zblur_warp_kernel<true><<<GRID, BLK, 0, stream>>>(u2, mov, vf, warped);
        }
        forces_xy_kernel<false><<<GRID, BLK, 0, stream>>>(warped, fix, vf, u2);
        zblur_warp_kernel<false><<<GRID, BLK, 0, stream>>>(u2, mov, vf, warped);
    }
}

// Round 7
// 766.880 us; speedup vs baseline: 1.0801x; 1.0801x over previous
//
#include <hip/hip_runtime.h>
#include <hip/hip_cooperative_groups.h>

namespace cg = cooperative_groups;

// Problem constants (match reference)
static constexpr int DIM = 128;
static constexpr int N = DIM * DIM * DIM;        // 2,097,152 voxels
static constexpr int ITERS = 20;
static constexpr float EPS = 1e-6f;

// Gaussian(sigma=1, radius=3) normalized weights
#define W0 0.39905028f
#define W1 0.24203624f
#define W2 0.05400559f
#define W3 0.00443305f

__device__ __forceinline__ int clamp_i(int v, int lo, int hi) {
    return min(max(v, lo), hi);
}

// ---------------------------------------------------------------------------
// Phase 1: fused forces (all 3 channels) + x-blur (register shuffles) +
// y-blur (LDS). R4-proven body (nt-hints reverted: R6 regression).
// Block b -> (z = b>>3, y0 = (b&7)*16): XCD k owns y-strip k for all z.
// LDS = 3*22*132*4 = 34848 B -> 4 blocks/CU.
// ---------------------------------------------------------------------------
#define ROWS 22            // 16 + 2*3 halo
#define SSTR 132           // padded row stride (floats), 16B-aligned
#define SC(c, r) ((((c) * ROWS) + (r)) * SSTR)
#define LDS_FLOATS (3 * ROWS * SSTR)

__device__ __forceinline__ void forces_phase(const float* __restrict__ wpd,
                                             const float* __restrict__ fix,
                                             const float* __restrict__ vf,
                                             float* __restrict__ u2,
                                             float* S, bool first, int b) {
    int z  = b >> 3;
    int y0 = (b & 7) << 4;

    // ---- Stage A+B: forces + x-blur -> S (704 items = 11 full waves)
    for (int e = threadIdx.x; e < ROWS * 32; e += 256) {
        int x4 = e & 31;
        int r  = e >> 5;
        int gy = y0 + r - 3;
        float4 rz = make_float4(0, 0, 0, 0);
        float4 ry = make_float4(0, 0, 0, 0);
        float4 rx = make_float4(0, 0, 0, 0);
        if (gy >= 0 && gy < 128) {
            int idx = (z << 14) + (gy << 7) + (x4 << 2);
            int xb = x4 << 2;

            float4 wc4 = *(const float4*)(wpd + idx);
            float4 fc4 = *(const float4*)(fix + idx);

            int iyp = (gy < 127) ? idx + 128   : idx;
            int iym = (gy > 0)   ? idx - 128   : idx;
            int izp = (z < 127)  ? idx + 16384 : idx;
            int izm = (z > 0)    ? idx - 16384 : idx;

            float4 wyp = *(const float4*)(wpd + iyp), wym = *(const float4*)(wpd + iym);
            float4 wzp = *(const float4*)(wpd + izp), wzm = *(const float4*)(wpd + izm);
            float4 fyp = *(const float4*)(fix + iyp), fym = *(const float4*)(fix + iym);
            float4 fzp = *(const float4*)(fix + izp), fzm = *(const float4*)(fix + izm);

            // x-halo via shuffle (replaces 4 scalar loads). Lane 0/31 (and
            // cross-row lane-32 boundary) garbage only reaches the unused
            // xi==0 / xi==127 one-sided arms.
            float wl = __shfl_up(wc4.w, 1);
            float wr = __shfl_down(wc4.x, 1);
            float fl = __shfl_up(fc4.w, 1);
            float fr = __shfl_down(fc4.x, 1);

            float wcv[4] = {wc4.x, wc4.y, wc4.z, wc4.w};
            float fcv[4] = {fc4.x, fc4.y, fc4.z, fc4.w};
            float wypv[4] = {wyp.x, wyp.y, wyp.z, wyp.w};
            float wymv[4] = {wym.x, wym.y, wym.z, wym.w};
            float wzpv[4] = {wzp.x, wzp.y, wzp.z, wzp.w};
            float wzmv[4] = {wzm.x, wzm.y, wzm.z, wzm.w};
            float fypv[4] = {fyp.x, fyp.y, fyp.z, fyp.w};
            float fymv[4] = {fym.x, fym.y, fym.z, fym.w};
            float fzpv[4] = {fzp.x, fzp.y, fzp.z, fzp.w};
            float fzmv[4] = {fzm.x, fzm.y, fzm.z, fzm.w};

            float4 vz4 = first ? make_float4(0, 0, 0, 0) : *(const float4*)(vf + idx);
            float4 vy4 = first ? make_float4(0, 0, 0, 0) : *(const float4*)(vf + N + idx);
            float4 vx4 = first ? make_float4(0, 0, 0, 0) : *(const float4*)(vf + 2 * N + idx);
            float vzv[4] = {vz4.x, vz4.y, vz4.z, vz4.w};
            float vyv[4] = {vy4.x, vy4.y, vy4.z, vy4.w};
            float vxv[4] = {vx4.x, vx4.y, vx4.z, vx4.w};

            float ozv[4], oyv[4], oxv[4];
#pragma unroll
            for (int i = 0; i < 4; ++i) {
                float wc = wcv[i], fc = fcv[i];
                float diff = wc - fc;

                float gwz = (z == 0)   ? (wzpv[i] - wc)
                          : (z == 127) ? (wc - wzmv[i])
                          : 0.5f * (wzpv[i] - wzmv[i]);
                float gfz = (z == 0)   ? (fzpv[i] - fc)
                          : (z == 127) ? (fc - fzmv[i])
                          : 0.5f * (fzpv[i] - fzmv[i]);
                float grz = 0.5f * (gwz + gfz);

                float gwy = (gy == 0)   ? (wypv[i] - wc)
                          : (gy == 127) ? (wc - wymv[i])
                          : 0.5f * (wypv[i] - wymv[i]);
                float gfy = (gy == 0)   ? (fypv[i] - fc)
                          : (gy == 127) ? (fc - fymv[i])
                          : 0.5f * (fypv[i] - fymv[i]);
                float gry = 0.5f * (gwy + gfy);

                float wleft  = (i == 0) ? wl : wcv[i - 1];
                float wright = (i == 3) ? wr : wcv[i + 1];
                float fleft  = (i == 0) ? fl : fcv[i - 1];
                float fright = (i == 3) ? fr : fcv[i + 1];
                int xi = xb + i;
                float gwx = (xi == 0)   ? (wright - wc)
                          : (xi == 127) ? (wc - wleft)
                          : 0.5f * (wright - wleft);
                float gfx = (xi == 0)   ? (fright - fc)
                          : (xi == 127) ? (fc - fleft)
                          : 0.5f * (fright - fleft);
                float grx = 0.5f * (gwx + gfx);

                float denom = grz * grz + gry * gry + grx * grx + diff * diff;
                float s = (denom > EPS) ? (diff / denom) : 0.0f;
                ozv[i] = vzv[i] + s * grz;
                oyv[i] = vyv[i] + s * gry;
                oxv[i] = vxv[i] + s * grx;
            }
            rz = make_float4(ozv[0], ozv[1], ozv[2], ozv[3]);
            ry = make_float4(oyv[0], oyv[1], oyv[2], oyv[3]);
            rx = make_float4(oxv[0], oxv[1], oxv[2], oxv[3]);
        }

        // x-blur in registers via lane shuffles (all 64 lanes active here;
        // OOB rows carry zeros = zero-pad).
        float4 vch[3] = {rz, ry, rx};
#pragma unroll
        for (int c = 0; c < 3; ++c) {
            float4 v0 = vch[c];
            float4 m1, p1;
            m1.x = __shfl_up(v0.x, 1);  m1.y = __shfl_up(v0.y, 1);
            m1.z = __shfl_up(v0.z, 1);  m1.w = __shfl_up(v0.w, 1);
            p1.x = __shfl_down(v0.x, 1); p1.y = __shfl_down(v0.y, 1);
            p1.z = __shfl_down(v0.z, 1); p1.w = __shfl_down(v0.w, 1);
            if (x4 == 0)  m1 = make_float4(0, 0, 0, 0);
            if (x4 == 31) p1 = make_float4(0, 0, 0, 0);
            float w[12] = {m1.x, m1.y, m1.z, m1.w,
                           v0.x, v0.y, v0.z, v0.w,
                           p1.x, p1.y, p1.z, p1.w};
            float o[4];
#pragma unroll
            for (int i = 0; i < 4; ++i) {
                o[i] = W3 * (w[i + 1] + w[i + 7]) + W2 * (w[i + 2] + w[i + 6])
                     + W1 * (w[i + 3] + w[i + 5]) + W0 * w[i + 4];
            }
            *(float4*)(S + SC(c, r) + (x4 << 2)) = make_float4(o[0], o[1], o[2], o[3]);
        }
    }
    __syncthreads();

    // ---- Stage C: y-blur S -> global u2 (16 rows x 32 float4 x 3 ch)
    for (int e = threadIdx.x; e < 16 * 32 * 3; e += 256) {
        int x4 = e & 31;
        int t2 = e >> 5;
        int y  = t2 & 15;
        int c  = t2 >> 4;
        const float* base = S + SC(c, y) + (x4 << 2);   // rows y..y+6 (halo offset)
        float4 v0 = *(const float4*)(base);
        float4 v1 = *(const float4*)(base + 1 * SSTR);
        float4 v2 = *(const float4*)(base + 2 * SSTR);
        float4 v3 = *(const float4*)(base + 3 * SSTR);
        float4 v4 = *(const float4*)(base + 4 * SSTR);
        float4 v5 = *(const float4*)(base + 5 * SSTR);
        float4 v6 = *(const float4*)(base + 6 * SSTR);
        float4 acc;
        acc.x = W3 * (v0.x + v6.x) + W2 * (v1.x + v5.x) + W1 * (v2.x + v4.x) + W0 * v3.x;
        acc.y = W3 * (v0.y + v6.y) + W2 * (v1.y + v5.y) + W1 * (v2.y + v4.y) + W0 * v3.y;
        acc.z = W3 * (v0.z + v6.z) + W2 * (v1.z + v5.z) + W1 * (v2.z + v4.z) + W0 * v3.z;
        acc.w = W3 * (v0.w + v6.w) + W2 * (v1.w + v5.w) + W1 * (v2.w + v4.w) + W0 * v3.w;
        *(float4*)(u2 + (size_t)c * N + ((size_t)z << 14) + ((y0 + y) << 7) + (x4 << 2)) = acc;
    }
}

// ---------------------------------------------------------------------------
// Phase 2: fused z-blur + trilinear warp (R4-proven body). Thread owns an
// (x,y) column x 8-z chunk for ALL 3 channels. Strip (b&7) matches phase 1.
// ---------------------------------------------------------------------------
__device__ __forceinline__ void zblur_phase(const float* __restrict__ u2,
                                            const float* __restrict__ mov,
                                            float* __restrict__ vf,
                                            float* __restrict__ warped,
                                            bool do_warp, int b) {
    int k  = b & 7;
    int j  = b >> 3;
    int lb = ((j & 15) << 6) + (k << 3) + (j >> 4);
    int g  = lb * 256 + threadIdx.x;          // 0 .. 262143 (bijective remap)
    int col = g & 16383;                      // (y<<7)|x
    int zc  = g >> 14;                        // 0..15
    int z0  = zc << 3;
    int x = col & 127, y = col >> 7;

    float bz[3][8];
#pragma unroll
    for (int c = 0; c < 3; ++c) {
        const float* inp = u2 + (size_t)c * N + col;
        float win[14];
#pragma unroll
        for (int i = 0; i < 14; ++i) {
            int zz = z0 - 3 + i;
            win[i] = (zz >= 0 && zz < 128) ? inp[(size_t)zz << 14] : 0.0f;
        }
#pragma unroll
        for (int k8 = 0; k8 < 8; ++k8) {
            bz[c][k8] = W3 * (win[k8] + win[k8 + 6]) + W2 * (win[k8 + 1] + win[k8 + 5])
                      + W1 * (win[k8 + 2] + win[k8 + 4]) + W0 * win[k8 + 3];
        }
        float* outp = vf + (size_t)c * N + col;
#pragma unroll
        for (int k8 = 0; k8 < 8; ++k8)
            outp[(size_t)(z0 + k8) << 14] = bz[c][k8];
    }

    if (do_warp) {
        for (int k8 = 0; k8 < 8; ++k8) {
            int z = z0 + k8;
            float cz = (float)z + bz[0][k8];
            float cy = (float)y + bz[1][k8];
            float cx = (float)x + bz[2][k8];

            float flz = floorf(cz), fly = floorf(cy), flx = floorf(cx);
            float fz = cz - flz, fy = cy - fly, fx = cx - flx;

            int zi = (int)flz, yi = (int)fly, xi = (int)flx;
            int z0c = clamp_i(zi, 0, DIM - 1), z1c = clamp_i(zi + 1, 0, DIM - 1);
            int y0c = clamp_i(yi, 0, DIM - 1), y1c = clamp_i(yi + 1, 0, DIM - 1);
            int x0c = clamp_i(xi, 0, DIM - 1), x1c = clamp_i(xi + 1, 0, DIM - 1);

            int b00 = (z0c << 14) + (y0c << 7);
            int b01 = (z0c << 14) + (y1c << 7);
            int b10 = (z1c << 14) + (y0c << 7);
            int b11 = (z1c << 14) + (y1c << 7);

            float v000 = mov[b00 + x0c], v001 = mov[b00 + x1c];
            float v010 = mov[b01 + x0c], v011 = mov[b01 + x1c];
            float v100 = mov[b10 + x0c], v101 = mov[b10 + x1c];
            float v110 = mov[b11 + x0c], v111 = mov[b11 + x1c];

            float c00 = v000 + fx * (v001 - v000);
            float c01 = v010 + fx * (v011 - v010);
            float c10 = v100 + fx * (v101 - v100);
            float c11 = v110 + fx * (v111 - v110);
            float c0 = c00 + fy * (c01 - c00);
            float c1 = c10 + fy * (c11 - c10);
            warped[((size_t)z << 14) + col] = c0 + fz * (c1 - c0);
        }
    }
}

// ---------------------------------------------------------------------------
// R7: persistent kernel with PER-STRIP producer-consumer sync instead of
// grid.sync per phase. Dependency analysis (strip = 16-row y-band = XCD):
//   phase-2(s,t)  reads u2 strip s only            -> needs cntA[s] == (t+1)*128
//   phase-2(s,t)  overwrites warped/vf strip s     -> old values read by
//                 phase-1(s-1..s+1, t)             -> also wait cntA[s+-1]
//   phase-1(s,t)  reads warped/vf rows 16s-4..16s+19 (strips s-1..s+1)
//                 written by phase-2(.., t-1)      -> needs cntB[s+-1,s] == t*128
//   u2 WAR: phase-1(s,t+1) overwrites u2 strip s; readers phase-2(s,t)
//                 covered by the cntB[s] wait.
// DAG is acyclic -> deadlock-free; all 1024 blocks co-resident (cooperative
// launch, 4 blk/CU). Release/acquire at AGENT scope handles cross-XCD L2
// writeback/invalidate. One grid.sync only for counter init.
// ---------------------------------------------------------------------------
__device__ __forceinline__ void wait_ge(unsigned int* c, unsigned int target) {
    while (__hip_atomic_load(c, __ATOMIC_ACQUIRE, __HIP_MEMORY_SCOPE_AGENT) < target)
        __builtin_amdgcn_s_sleep(1);
}

__global__ __launch_bounds__(256, 4) void demons_persistent(const float* mov,
                                                            const float* fix,
                                                            float* vf,
                                                            float* warped,
                                                            float* u2,
                                                            unsigned int* cnt) {
    cg::grid_group grid = cg::this_grid();
    __shared__ float S[LDS_FLOATS];
    int b = blockIdx.x;
    int s = b & 7;                       // strip id (same in both phases)
    unsigned int* cntA = cnt;            // [8] phase-1 completions per strip
    unsigned int* cntB = cnt + 8;        // [8] phase-2 completions per strip

    if (b == 0 && threadIdx.x < 16) cnt[threadIdx.x] = 0u;
    grid.sync();                         // counters visible grid-wide

    for (int it = 0; it < ITERS; ++it) {
        bool first = (it == 0);
        if (!first) {
            if (threadIdx.x == 0) {
                unsigned int tgt = (unsigned int)it * 128u;
                if (s > 0) wait_ge(&cntB[s - 1], tgt);
                wait_ge(&cntB[s], tgt);
                if (s < 7) wait_ge(&cntB[s + 1], tgt);
            }
            __syncthreads();
        }
        forces_phase(first ? mov : warped, fix, vf, u2, S, first, b);
        __syncthreads();                 // block's u2 stores drained
        if (threadIdx.x == 0) {
            __hip_atomic_fetch_add(&cntA[s], 1u, __ATOMIC_RELEASE, __HIP_MEMORY_SCOPE_AGENT);
            unsigned int tgt = (unsigned int)(it + 1) * 128u;
            if (s > 0) wait_ge(&cntA[s - 1], tgt);
            wait_ge(&cntA[s], tgt);
            if (s < 7) wait_ge(&cntA[s + 1], tgt);
        }
        __syncthreads();
        zblur_phase(u2, mov, vf, warped, it < ITERS - 1, b);
        if (it < ITERS - 1) {
            __syncthreads();             // block's vf/warped stores drained
            if (threadIdx.x == 0)
                __hip_atomic_fetch_add(&cntB[s], 1u, __ATOMIC_RELEASE, __HIP_MEMORY_SCOPE_AGENT);
        }
    }
}

// ---------------------------------------------------------------------------
// Fallback path (proven R2 structure): separate launches per phase.
// ---------------------------------------------------------------------------
template <bool FIRST>
__global__ __launch_bounds__(256, 4) void forces_xy_kernel(const float* __restrict__ wpd,
                                                           const float* __restrict__ fix,
                                                           const float* __restrict__ vf,
                                                           float* __restrict__ u2) {
    __shared__ float S[LDS_FLOATS];
    forces_phase(wpd, fix, vf, u2, S, FIRST, blockIdx.x);
}

template <bool DO_WARP>
__global__ __launch_bounds__(256, 4) void zblur_warp_kernel(const float* __restrict__ u2,
                                                            const float* __restrict__ mov,
                                                            float* __restrict__ vf,
                                                            float* __restrict__ warped) {
    zblur_phase(u2, mov, vf, warped, DO_WARP, blockIdx.x);
}

extern "C" void kernel_launch(void* const* d_in, const int* in_sizes, int n_in,
                              void* d_out, int out_size, void* d_ws, size_t ws_size,
                              hipStream_t stream) {
    const float* mov = (const float*)d_in[0];
    const float* fix = (const float*)d_in[1];
    float* vf = (float*)d_out;          // (3, N) — lives in d_out throughout
    float* ws = (float*)d_ws;
    float* warped = ws;                 // N floats
    float* u2     = ws + (size_t)N;     // 3N floats (xy-blurred forces)
    unsigned int* cnt = (unsigned int*)(ws + (size_t)4 * N);  // 16 uints

    const int BLK = 256;
    const int GRID = 1024;

    // Decide cooperative support once (host-only queries; graph-capture safe).
    static int coop_ok = -1;
    if (coop_ok < 0) {
        int dev = 0;
        (void)hipGetDevice(&dev);
        int coop = 0;
        (void)hipDeviceGetAttribute(&coop, hipDeviceAttributeCooperativeLaunch, dev);
        int ncu = 0;
        (void)hipDeviceGetAttribute(&ncu, hipDeviceAttributeMultiprocessorCount, dev);
        int occ = 0;
        (void)hipOccupancyMaxActiveBlocksPerMultiprocessor(&occ, demons_persistent, BLK, 0);
        coop_ok = (coop && (long long)occ * ncu >= GRID &&
                   ws_size >= (size_t)4 * N * sizeof(float) + 64) ? 1 : 0;
    }

    if (coop_ok) {
        void* args[] = {(void*)&mov, (void*)&fix, (void*)&vf, (void*)&warped,
                        (void*)&u2, (void*)&cnt};
        (void)hipLaunchCooperativeKernel(demons_persistent, dim3(GRID), dim3(BLK),
                                         args, 0, stream);
    } else {
        forces_xy_kernel<true><<<GRID, BLK, 0, stream>>>(mov, fix, nullptr, u2);
        zblur_warp_kernel<true><<<GRID, BLK, 0, stream>>>(u2, mov, vf, warped);
        for (int it = 1; it < ITERS - 1; ++it) {
            forces_xy_kernel<false><<<GRID, BLK, 0, stream>>>(warped, fix, vf, u2);
            zblur_warp_kernel<true><<<GRID, BLK, 0, stream>>>(u2, mov, vf, warped);
        }
        forces_xy_kernel<false><<<GRID, BLK, 0, stream>>>(warped, fix, vf, u2);
        zblur_warp_kernel<false><<<GRID, BLK, 0, stream>>>(u2, mov, vf, warped);
    }
}

// Round 9
// 763.863 us; speedup vs baseline: 1.0844x; 1.0040x over previous
//
#include <hip/hip_runtime.h>
#include <hip/hip_cooperative_groups.h>

namespace cg = cooperative_groups;

// Problem constants (match reference)
static constexpr int DIM = 128;
static constexpr int N = DIM * DIM * DIM;        // 2,097,152 voxels
static constexpr int ITERS = 20;
static constexpr float EPS = 1e-6f;

// Gaussian(sigma=1, radius=3) normalized weights
#define W0 0.39905028f
#define W1 0.24203624f
#define W2 0.05400559f
#define W3 0.00443305f

__device__ __forceinline__ int clamp_i(int v, int lo, int hi) {
    return min(max(v, lo), hi);
}

// ---------------------------------------------------------------------------
// Phase 1: fused forces (all 3 channels) + x-blur (register shuffles) +
// y-blur (LDS). R4-proven body. Block b -> (z = b>>3, y0 = (b&7)*16):
// XCD k owns y-strip k for all z. LDS = 34848 B -> 4 blocks/CU.
// ---------------------------------------------------------------------------
#define ROWS 22            // 16 + 2*3 halo
#define SSTR 132           // padded row stride (floats), 16B-aligned
#define SC(c, r) ((((c) * ROWS) + (r)) * SSTR)
#define LDS_FLOATS (3 * ROWS * SSTR)

__device__ __forceinline__ void forces_phase(const float* __restrict__ wpd,
                                             const float* __restrict__ fix,
                                             const float* __restrict__ vf,
                                             float* __restrict__ u2,
                                             float* S, bool first, int b) {
    int z  = b >> 3;
    int y0 = (b & 7) << 4;

    // ---- Stage A+B: forces + x-blur -> S (704 items = 11 full waves)
    for (int e = threadIdx.x; e < ROWS * 32; e += 256) {
        int x4 = e & 31;
        int r  = e >> 5;
        int gy = y0 + r - 3;
        float4 rz = make_float4(0, 0, 0, 0);
        float4 ry = make_float4(0, 0, 0, 0);
        float4 rx = make_float4(0, 0, 0, 0);
        if (gy >= 0 && gy < 128) {
            int idx = (z << 14) + (gy << 7) + (x4 << 2);
            int xb = x4 << 2;

            float4 wc4 = *(const float4*)(wpd + idx);
            float4 fc4 = *(const float4*)(fix + idx);

            int iyp = (gy < 127) ? idx + 128   : idx;
            int iym = (gy > 0)   ? idx - 128   : idx;
            int izp = (z < 127)  ? idx + 16384 : idx;
            int izm = (z > 0)    ? idx - 16384 : idx;

            float4 wyp = *(const float4*)(wpd + iyp), wym = *(const float4*)(wpd + iym);
            float4 wzp = *(const float4*)(wpd + izp), wzm = *(const float4*)(wpd + izm);
            float4 fyp = *(const float4*)(fix + iyp), fym = *(const float4*)(fix + iym);
            float4 fzp = *(const float4*)(fix + izp), fzm = *(const float4*)(fix + izm);

            // x-halo via shuffle (replaces 4 scalar loads). Lane 0/31 (and
            // cross-row lane-32 boundary) garbage only reaches the unused
            // xi==0 / xi==127 one-sided arms.
            float wl = __shfl_up(wc4.w, 1);
            float wr = __shfl_down(wc4.x, 1);
            float fl = __shfl_up(fc4.w, 1);
            float fr = __shfl_down(fc4.x, 1);

            float wcv[4] = {wc4.x, wc4.y, wc4.z, wc4.w};
            float fcv[4] = {fc4.x, fc4.y, fc4.z, fc4.w};
            float wypv[4] = {wyp.x, wyp.y, wyp.z, wyp.w};
            float wymv[4] = {wym.x, wym.y, wym.z, wym.w};
            float wzpv[4] = {wzp.x, wzp.y, wzp.z, wzp.w};
            float wzmv[4] = {wzm.x, wzm.y, wzm.z, wzm.w};
            float fypv[4] = {fyp.x, fyp.y, fyp.z, fyp.w};
            float fymv[4] = {fym.x, fym.y, fym.z, fym.w};
            float fzpv[4] = {fzp.x, fzp.y, fzp.z, fzp.w};
            float fzmv[4] = {fzm.x, fzm.y, fzm.z, fzm.w};

            float4 vz4 = first ? make_float4(0, 0, 0, 0) : *(const float4*)(vf + idx);
            float4 vy4 = first ? make_float4(0, 0, 0, 0) : *(const float4*)(vf + N + idx);
            float4 vx4 = first ? make_float4(0, 0, 0, 0) : *(const float4*)(vf + 2 * N + idx);
            float vzv[4] = {vz4.x, vz4.y, vz4.z, vz4.w};
            float vyv[4] = {vy4.x, vy4.y, vy4.z, vy4.w};
            float vxv[4] = {vx4.x, vx4.y, vx4.z, vx4.w};

            float ozv[4], oyv[4], oxv[4];
#pragma unroll
            for (int i = 0; i < 4; ++i) {
                float wc = wcv[i], fc = fcv[i];
                float diff = wc - fc;

                float gwz = (z == 0)   ? (wzpv[i] - wc)
                          : (z == 127) ? (wc - wzmv[i])
                          : 0.5f * (wzpv[i] - wzmv[i]);
                float gfz = (z == 0)   ? (fzpv[i] - fc)
                          : (z == 127) ? (fc - fzmv[i])
                          : 0.5f * (fzpv[i] - fzmv[i]);
                float grz = 0.5f * (gwz + gfz);

                float gwy = (gy == 0)   ? (wypv[i] - wc)
                          : (gy == 127) ? (wc - wymv[i])
                          : 0.5f * (wypv[i] - wymv[i]);
                float gfy = (gy == 0)   ? (fypv[i] - fc)
                          : (gy == 127) ? (fc - fymv[i])
                          : 0.5f * (fypv[i] - fymv[i]);
                float gry = 0.5f * (gwy + gfy);

                float wleft  = (i == 0) ? wl : wcv[i - 1];
                float wright = (i == 3) ? wr : wcv[i + 1];
                float fleft  = (i == 0) ? fl : fcv[i - 1];
                float fright = (i == 3) ? fr : fcv[i + 1];
                int xi = xb + i;
                float gwx = (xi == 0)   ? (wright - wc)
                          : (xi == 127) ? (wc - wleft)
                          : 0.5f * (wright - wleft);
                float gfx = (xi == 0)   ? (fright - fc)
                          : (xi == 127) ? (fc - fleft)
                          : 0.5f * (fright - fleft);
                float grx = 0.5f * (gwx + gfx);

                float denom = grz * grz + gry * gry + grx * grx + diff * diff;
                float s = (denom > EPS) ? (diff / denom) : 0.0f;
                ozv[i] = vzv[i] + s * grz;
                oyv[i] = vyv[i] + s * gry;
                oxv[i] = vxv[i] + s * grx;
            }
            rz = make_float4(ozv[0], ozv[1], ozv[2], ozv[3]);
            ry = make_float4(oyv[0], oyv[1], oyv[2], oyv[3]);
            rx = make_float4(oxv[0], oxv[1], oxv[2], oxv[3]);
        }

        // x-blur in registers via lane shuffles (all 64 lanes active here;
        // OOB rows carry zeros = zero-pad).
        float4 vch[3] = {rz, ry, rx};
#pragma unroll
        for (int c = 0; c < 3; ++c) {
            float4 v0 = vch[c];
            float4 m1, p1;
            m1.x = __shfl_up(v0.x, 1);  m1.y = __shfl_up(v0.y, 1);
            m1.z = __shfl_up(v0.z, 1);  m1.w = __shfl_up(v0.w, 1);
            p1.x = __shfl_down(v0.x, 1); p1.y = __shfl_down(v0.y, 1);
            p1.z = __shfl_down(v0.z, 1); p1.w = __shfl_down(v0.w, 1);
            if (x4 == 0)  m1 = make_float4(0, 0, 0, 0);
            if (x4 == 31) p1 = make_float4(0, 0, 0, 0);
            float w[12] = {m1.x, m1.y, m1.z, m1.w,
                           v0.x, v0.y, v0.z, v0.w,
                           p1.x, p1.y, p1.z, p1.w};
            float o[4];
#pragma unroll
            for (int i = 0; i < 4; ++i) {
                o[i] = W3 * (w[i + 1] + w[i + 7]) + W2 * (w[i + 2] + w[i + 6])
                     + W1 * (w[i + 3] + w[i + 5]) + W0 * w[i + 4];
            }
            *(float4*)(S + SC(c, r) + (x4 << 2)) = make_float4(o[0], o[1], o[2], o[3]);
        }
    }
    __syncthreads();

    // ---- Stage C: y-blur S -> global u2 (16 rows x 32 float4 x 3 ch)
    for (int e = threadIdx.x; e < 16 * 32 * 3; e += 256) {
        int x4 = e & 31;
        int t2 = e >> 5;
        int y  = t2 & 15;
        int c  = t2 >> 4;
        const float* base = S + SC(c, y) + (x4 << 2);   // rows y..y+6 (halo offset)
        float4 v0 = *(const float4*)(base);
        float4 v1 = *(const float4*)(base + 1 * SSTR);
        float4 v2 = *(const float4*)(base + 2 * SSTR);
        float4 v3 = *(const float4*)(base + 3 * SSTR);
        float4 v4 = *(const float4*)(base + 4 * SSTR);
        float4 v5 = *(const float4*)(base + 5 * SSTR);
        float4 v6 = *(const float4*)(base + 6 * SSTR);
        float4 acc;
        acc.x = W3 * (v0.x + v6.x) + W2 * (v1.x + v5.x) + W1 * (v2.x + v4.x) + W0 * v3.x;
        acc.y = W3 * (v0.y + v6.y) + W2 * (v1.y + v5.y) + W1 * (v2.y + v4.y) + W0 * v3.y;
        acc.z = W3 * (v0.z + v6.z) + W2 * (v1.z + v5.z) + W1 * (v2.z + v4.z) + W0 * v3.z;
        acc.w = W3 * (v0.w + v6.w) + W2 * (v1.w + v5.w) + W1 * (v2.w + v4.w) + W0 * v3.w;
        *(float4*)(u2 + (size_t)c * N + ((size_t)z << 14) + ((y0 + y) << 7) + (x4 << 2)) = acc;
    }
}

// ---------------------------------------------------------------------------
// Phase 2: fused z-blur + trilinear warp (R4-proven body). Thread owns an
// (x,y) column x 8-z chunk for ALL 3 channels. Strip (b&7) matches phase 1.
// ---------------------------------------------------------------------------
__device__ __forceinline__ void zblur_phase(const float* __restrict__ u2,
                                            const float* __restrict__ mov,
                                            float* __restrict__ vf,
                                            float* __restrict__ warped,
                                            bool do_warp, int b) {
    int k  = b & 7;
    int j  = b >> 3;
    int lb = ((j & 15) << 6) + (k << 3) + (j >> 4);
    int g  = lb * 256 + threadIdx.x;          // 0 .. 262143 (bijective remap)
    int col = g & 16383;                      // (y<<7)|x
    int zc  = g >> 14;                        // 0..15
    int z0  = zc << 3;
    int x = col & 127, y = col >> 7;

    float bz[3][8];
#pragma unroll
    for (int c = 0; c < 3; ++c) {
        const float* inp = u2 + (size_t)c * N + col;
        float win[14];
#pragma unroll
        for (int i = 0; i < 14; ++i) {
            int zz = z0 - 3 + i;
            win[i] = (zz >= 0 && zz < 128) ? inp[(size_t)zz << 14] : 0.0f;
        }
#pragma unroll
        for (int k8 = 0; k8 < 8; ++k8) {
            bz[c][k8] = W3 * (win[k8] + win[k8 + 6]) + W2 * (win[k8 + 1] + win[k8 + 5])
                      + W1 * (win[k8 + 2] + win[k8 + 4]) + W0 * win[k8 + 3];
        }
        float* outp = vf + (size_t)c * N + col;
#pragma unroll
        for (int k8 = 0; k8 < 8; ++k8)
            outp[(size_t)(z0 + k8) << 14] = bz[c][k8];
    }

    if (do_warp) {
        for (int k8 = 0; k8 < 8; ++k8) {
            int z = z0 + k8;
            float cz = (float)z + bz[0][k8];
            float cy = (float)y + bz[1][k8];
            float cx = (float)x + bz[2][k8];

            float flz = floorf(cz), fly = floorf(cy), flx = floorf(cx);
            float fz = cz - flz, fy = cy - fly, fx = cx - flx;

            int zi = (int)flz, yi = (int)fly, xi = (int)flx;
            int z0c = clamp_i(zi, 0, DIM - 1), z1c = clamp_i(zi + 1, 0, DIM - 1);
            int y0c = clamp_i(yi, 0, DIM - 1), y1c = clamp_i(yi + 1, 0, DIM - 1);
            int x0c = clamp_i(xi, 0, DIM - 1), x1c = clamp_i(xi + 1, 0, DIM - 1);

            int b00 = (z0c << 14) + (y0c << 7);
            int b01 = (z0c << 14) + (y1c << 7);
            int b10 = (z1c << 14) + (y0c << 7);
            int b11 = (z1c << 14) + (y1c << 7);

            float v000 = mov[b00 + x0c], v001 = mov[b00 + x1c];
            float v010 = mov[b01 + x0c], v011 = mov[b01 + x1c];
            float v100 = mov[b10 + x0c], v101 = mov[b10 + x1c];
            float v110 = mov[b11 + x0c], v111 = mov[b11 + x1c];

            float c00 = v000 + fx * (v001 - v000);
            float c01 = v010 + fx * (v011 - v010);
            float c10 = v100 + fx * (v101 - v100);
            float c11 = v110 + fx * (v111 - v110);
            float c0 = c00 + fy * (c01 - c00);
            float c1 = c10 + fy * (c11 - c10);
            warped[((size_t)z << 14) + col] = c0 + fz * (c1 - c0);
        }
    }
}

// ---------------------------------------------------------------------------
// R9: z-granular producer-consumer sync (hardened R8).
//   flagA[s][z]  = iter count of completed phase-1 for (strip s, plane z)
//   flagB[s][zc] = 8x iter count for phase-2 chunk (8 writer blocks/chunk)
// Dependencies (superset ranges, all strictly earlier in (iter, phase)):
//   phase-2(s,zc,t): A[s'][z'] >= t+1, s' in {s-1..s+1}, z' in [8zc-3,8zc+10]
//   phase-1(s,z,t):  B[s'][zc'] >= t*8, s' in {s-1..s+1},
//                    zc' in [(z-10)>>3, (z+3)>>3]
// DAG strictly ordered by (iter, phase) -> acyclic -> deadlock-free with all
// 1024 blocks co-resident (cooperative launch). Flag polling is PARALLEL:
// each waiting thread spins on one flag, then __syncthreads (R8 had thread 0
// serially polling up to 42 flags).
// ---------------------------------------------------------------------------
__device__ __forceinline__ void wait_ge(unsigned int* c, unsigned int target) {
    while (__hip_atomic_load(c, __ATOMIC_ACQUIRE, __HIP_MEMORY_SCOPE_AGENT) < target)
        __builtin_amdgcn_s_sleep(1);
}

__global__ __launch_bounds__(256, 4) void demons_persistent(const float* mov,
                                                            const float* fix,
                                                            float* vf,
                                                            float* warped,
                                                            float* u2,
                                                            unsigned int* flags) {
    cg::grid_group grid = cg::this_grid();
    __shared__ float S[LDS_FLOATS];
    int b = blockIdx.x;
    int s = b & 7;                        // strip id (same in both phases)
    int z = b >> 3;                       // phase-1 plane
    int zc = (b >> 3) & 15;               // phase-2 z-chunk (== lb>>6)

    unsigned int* flagA = flags;          // [8][128]
    unsigned int* flagB = flags + 1024;   // [8][16]

    if (b == 0) {
        for (int i = threadIdx.x; i < 1024 + 128; i += 256) flags[i] = 0u;
    }
    grid.sync();                          // zeroed flags visible grid-wide

    int slo = (s > 0) ? s - 1 : 0;
    int shi = (s < 7) ? s + 1 : 7;
    int ns  = shi - slo + 1;

    // phase-1 wait set: B[slo..shi][zclo..zchi]
    int zclo = (z >= 10) ? ((z - 10) >> 3) : 0;
    int zchi = ((z + 3 > 127) ? 127 : (z + 3)) >> 3;
    int ncB  = zchi - zclo + 1;
    int totB = ns * ncB;                  // <= 9

    // phase-2 wait set: A[slo..shi][plo..phi]
    int plo = (zc * 8 >= 3) ? zc * 8 - 3 : 0;
    int phi = (zc * 8 + 10 > 127) ? 127 : zc * 8 + 10;
    int ncA = phi - plo + 1;
    int totA = ns * ncA;                  // <= 42

    int tid = threadIdx.x;

    for (int it = 0; it < ITERS; ++it) {
        bool first = (it == 0);
        if (!first) {
            if (tid < totB) {
                int ss = slo + tid / ncB;
                int c2 = zclo + tid % ncB;
                wait_ge(&flagB[ss * 16 + c2], (unsigned int)it * 8u);
            }
            __syncthreads();
        }
        forces_phase(first ? mov : warped, fix, vf, u2, S, first, b);
        __syncthreads();                  // block's u2 stores drained
        if (tid == 0)
            __hip_atomic_store(&flagA[s * 128 + z], (unsigned int)(it + 1),
                               __ATOMIC_RELEASE, __HIP_MEMORY_SCOPE_AGENT);
        if (tid < totA) {
            int ss = slo + tid / ncA;
            int p  = plo + tid % ncA;
            wait_ge(&flagA[ss * 128 + p], (unsigned int)(it + 1));
        }
        __syncthreads();
        zblur_phase(u2, mov, vf, warped, it < ITERS - 1, b);
        if (it < ITERS - 1) {
            __syncthreads();              // block's vf/warped stores drained
            if (tid == 0)
                __hip_atomic_fetch_add(&flagB[s * 16 + zc], 1u,
                                       __ATOMIC_RELEASE, __HIP_MEMORY_SCOPE_AGENT);
        }
    }
}

// ---------------------------------------------------------------------------
// Fallback path (proven R2 structure): separate launches per phase.
// ---------------------------------------------------------------------------
template <bool FIRST>
__global__ __launch_bounds__(256, 4) void forces_xy_kernel(const float* __restrict__ wpd,
                                                           const float* __restrict__ fix,
                                                           const float* __restrict__ vf,
                                                           float* __restrict__ u2) {
    __shared__ float S[LDS_FLOATS];
    forces_phase(wpd, fix, vf, u2, S, FIRST, blockIdx.x);
}

template <bool DO_WARP>
__global__ __launch_bounds__(256, 4) void zblur_warp_kernel(const float* __restrict__ u2,
                                                            const float* __restrict__ mov,
                                                            float* __restrict__ vf,
                                                            float* __restrict__ warped) {
    zblur_phase(u2, mov, vf, warped, DO_WARP, blockIdx.x);
}

static void launch_fallback(const float* mov, const float* fix, float* vf,
                            float* warped, float* u2, hipStream_t stream) {
    const int BLK = 256, GRID = 1024;
    forces_xy_kernel<true><<<GRID, BLK, 0, stream>>>(mov, fix, nullptr, u2);
    zblur_warp_kernel<true><<<GRID, BLK, 0, stream>>>(u2, mov, vf, warped);
    for (int it = 1; it < ITERS - 1; ++it) {
        forces_xy_kernel<false><<<GRID, BLK, 0, stream>>>(warped, fix, vf, u2);
        zblur_warp_kernel<true><<<GRID, BLK, 0, stream>>>(u2, mov, vf, warped);
    }
    forces_xy_kernel<false><<<GRID, BLK, 0, stream>>>(warped, fix, vf, u2);
    zblur_warp_kernel<false><<<GRID, BLK, 0, stream>>>(u2, mov, vf, warped);
}

extern "C" void kernel_launch(void* const* d_in, const int* in_sizes, int n_in,
                              void* d_out, int out_size, void* d_ws, size_t ws_size,
                              hipStream_t stream) {
    const float* mov = (const float*)d_in[0];
    const float* fix = (const float*)d_in[1];
    float* vf = (float*)d_out;          // (3, N) — lives in d_out throughout
    float* ws = (float*)d_ws;
    float* warped = ws;                 // N floats
    float* u2     = ws + (size_t)N;     // 3N floats (xy-blurred forces)
    unsigned int* flags = (unsigned int*)(ws + (size_t)4 * N);  // 1152 uints

    const int BLK = 256;
    const int GRID = 1024;

    // Decide cooperative support once (host-only queries; graph-capture safe).
    static int coop_ok = -1;
    if (coop_ok < 0) {
        int dev = 0;
        (void)hipGetDevice(&dev);
        int coop = 0;
        (void)hipDeviceGetAttribute(&coop, hipDeviceAttributeCooperativeLaunch, dev);
        int ncu = 0;
        (void)hipDeviceGetAttribute(&ncu, hipDeviceAttributeMultiprocessorCount, dev);
        int occ = 0;
        (void)hipOccupancyMaxActiveBlocksPerMultiprocessor(&occ, demons_persistent, BLK, 0);
        coop_ok = (coop && (long long)occ * ncu >= GRID &&
                   ws_size >= (size_t)4 * N * sizeof(float) + 1152 * sizeof(unsigned int)) ? 1 : 0;
    }

    if (coop_ok) {
        void* args[] = {(void*)&mov, (void*)&fix, (void*)&vf, (void*)&warped,
                        (void*)&u2, (void*)&flags};
        hipError_t err = hipLaunchCooperativeKernel(demons_persistent, dim3(GRID),
                                                    dim3(BLK), args, 0, stream);
        if (err != hipSuccess) {
            coop_ok = 0;                 // don't retry next call
            launch_fallback(mov, fix, vf, warped, u2, stream);
        }
    } else {
        launch_fallback(mov, fix, vf, warped, u2, stream);
    }
}